// Round 10
// baseline (144.785 us; speedup 1.0000x reference)
//
#include <hip/hip_runtime.h>

#define T_TOK 8192
#define DIM   512
#define HID   1024
#define OUTD  512
#define NE    8

typedef __attribute__((ext_vector_type(8))) short short8v;   // 8 bf16 (4 VGPRs)
typedef __attribute__((ext_vector_type(4))) float f32x4;

__device__ __forceinline__ unsigned short f2bf(float f) {
  unsigned int u = __builtin_bit_cast(unsigned int, f);
  u += 0x7fffu + ((u >> 16) & 1u);            // RNE, finite inputs
  return (unsigned short)(u >> 16);
}

__device__ __forceinline__ float bf2f(unsigned short h) {
  unsigned int u = ((unsigned int)h) << 16;
  return __builtin_bit_cast(float, u);
}

__device__ __forceinline__ void gload_lds16(const void* g, void* l) {
  __builtin_amdgcn_global_load_lds(
      (__attribute__((address_space(1))) void*)g,
      (__attribute__((address_space(3))) void*)l, 16, 0, 0);
}

// gelu tanh-approx, exact identity: 0.5v(1+tanh(u)) = v * sigmoid(2u)
__device__ __forceinline__ float gelu_f(float v) {
  const float c0 = 0.7978845608028654f;       // sqrt(2/pi), jax approximate=True
  float u = c0 * (v + 0.044715f * v * v * v);
  return v / (1.0f + __expf(-2.0f * u));
}

// ---- merged transpose+cvt for W1 and W2: [E][R][C] f32 -> [E][C][R] bf16 ----
__global__ __launch_bounds__(256) void k_trans_all(
    const float* __restrict__ W1, const float* __restrict__ W2,
    unsigned short* __restrict__ W1t, unsigned short* __restrict__ W2t) {
  __shared__ float tile[32][33];
  int bid = blockIdx.x;
  int which = bid >> 12;            // 0: W1 (512x1024), 1: W2 (1024x512)
  int r = bid & 4095;
  int e = r >> 9;
  int t = r & 511;
  int R = which ? HID : DIM;
  int C = which ? OUTD : HID;
  int tx, ty;
  if (which == 0) { ty = t >> 5; tx = t & 31; }   // 16 x 32 tiles
  else            { ty = t >> 4; tx = t & 15; }   // 32 x 16 tiles
  const float* inE = (which ? W2 : W1) + (size_t)e * R * C;
  unsigned short* outE = (which ? W2t : W1t) + (size_t)e * R * C;
  int c0 = tx * 32, r0 = ty * 32;
  int x = threadIdx.x, y = threadIdx.y;
#pragma unroll
  for (int i = 0; i < 32; i += 8)
    tile[y + i][x] = inE[(size_t)(r0 + y + i) * C + (c0 + x)];
  __syncthreads();
#pragma unroll
  for (int i = 0; i < 32; i += 8)
    outE[(size_t)(c0 + y + i) * R + (r0 + x)] = f2bf(tile[x][y + i]);
}

// ---- router: one wave per token, f32 logits -> softmax -> top2 (NO atomics) ----
__global__ __launch_bounds__(256) void k_router(
    const float* __restrict__ x, const float* __restrict__ Wg,
    int* __restrict__ top_e, float* __restrict__ top_p) {
  int lane = threadIdx.x & 63;
  int t = blockIdx.x * 4 + (threadIdx.x >> 6);
  const float* xr = x + (size_t)t * DIM;
  int j0 = lane * 8;
  float4 xa = *(const float4*)(xr + j0);
  float4 xb = *(const float4*)(xr + j0 + 4);
  float xl[8] = {xa.x, xa.y, xa.z, xa.w, xb.x, xb.y, xb.z, xb.w};
  float acc[8] = {0.f,0.f,0.f,0.f,0.f,0.f,0.f,0.f};
#pragma unroll
  for (int jj = 0; jj < 8; ++jj) {
    float4 w0 = *(const float4*)(Wg + (size_t)(j0 + jj) * NE);
    float4 w1 = *(const float4*)(Wg + (size_t)(j0 + jj) * NE + 4);
    acc[0] += xl[jj] * w0.x; acc[1] += xl[jj] * w0.y;
    acc[2] += xl[jj] * w0.z; acc[3] += xl[jj] * w0.w;
    acc[4] += xl[jj] * w1.x; acc[5] += xl[jj] * w1.y;
    acc[6] += xl[jj] * w1.z; acc[7] += xl[jj] * w1.w;
  }
#pragma unroll
  for (int off = 32; off >= 1; off >>= 1) {
#pragma unroll
    for (int e2 = 0; e2 < 8; ++e2) acc[e2] += __shfl_xor(acc[e2], off, 64);
  }
  if (lane == 0) {
    float m = acc[0];
#pragma unroll
    for (int e2 = 1; e2 < 8; ++e2) m = fmaxf(m, acc[e2]);
    float p[8]; float s = 0.f;
#pragma unroll
    for (int e2 = 0; e2 < 8; ++e2) { p[e2] = expf(acc[e2] - m); s += p[e2]; }
    float inv = 1.f / s;
    int i0 = 0;
#pragma unroll
    for (int e2 = 1; e2 < 8; ++e2) if (p[e2] > p[i0]) i0 = e2;
    int i1 = (i0 == 0) ? 1 : 0;
#pragma unroll
    for (int e2 = 0; e2 < 8; ++e2) if (e2 != i0 && p[e2] > p[i1]) i1 = e2;
    top_e[t * 2] = i0;  top_e[t * 2 + 1] = i1;
    top_p[t * 2] = p[i0] * inv;  top_p[t * 2 + 1] = p[i1] * inv;
  }
}

// ---- plan: deterministic local ranks via ballot, per-block expert counts ----
__global__ __launch_bounds__(256) void k_plan(
    const int* __restrict__ top_e, int* __restrict__ localRank,
    int* __restrict__ blockCounts) {
  __shared__ int cnt[4][NE];
  __shared__ int wbase[4][NE];
  int tid = threadIdx.x, lane = tid & 63, w = tid >> 6;
  int a = blockIdx.x * 256 + tid;
  int e = top_e[a];
  int rank = 0;
#pragma unroll
  for (int e2 = 0; e2 < NE; ++e2) {
    unsigned long long m = __ballot(e == e2);
    if (e == e2) rank = __popcll(m & ((1ULL << lane) - 1ULL));
    if (lane == 0) cnt[w][e2] = __popcll(m);
  }
  __syncthreads();
  if (tid < NE) {
    int s = 0;
#pragma unroll
    for (int w2 = 0; w2 < 4; ++w2) { wbase[w2][tid] = s; s += cnt[w2][tid]; }
    blockCounts[blockIdx.x * NE + tid] = s;
  }
  __syncthreads();
  localRank[a] = wbase[w][e] + rank;
}

// ---- scan: per-expert prefix over blocks + global expert offsets ----
__global__ void k_scan2(const int* __restrict__ blockCounts, int* __restrict__ baseBlk,
                        int* __restrict__ offs, int nBlocks) {
  __shared__ int tot[NE];
  int tid = threadIdx.x;
  if (tid < NE) {
    int s = 0;
    for (int b = 0; b < nBlocks; ++b) { baseBlk[b * NE + tid] = s; s += blockCounts[b * NE + tid]; }
    tot[tid] = s;
  }
  __syncthreads();
  if (tid == 0) {
    int s = 0;
    for (int e = 0; e < NE; ++e) { offs[e] = s; s += tot[e]; }
    offs[NE] = s;   // == 2*T_TOK
  }
}

// ---- scatter: pos = offs[e] + baseBlk[b][e] + localRank (NO atomics) ----
__global__ __launch_bounds__(256) void k_scatter(
    const float* __restrict__ x, const int* __restrict__ top_e,
    const int* __restrict__ localRank, const int* __restrict__ baseBlk,
    const int* __restrict__ offs, int* __restrict__ pos_of,
    unsigned short* __restrict__ Xp) {
  int lane = threadIdx.x & 63;
  int a = blockIdx.x * 4 + (threadIdx.x >> 6);   // 0..16383
  int t = a >> 1;
  int e = top_e[a];
  int pos = offs[e] + baseBlk[(a >> 8) * NE + e] + localRank[a];
  if (lane == 0) pos_of[a] = pos;
  const float* xr = x + (size_t)t * DIM + lane * 8;
  float4 xa = *(const float4*)xr;
  float4 xb = *(const float4*)(xr + 4);
  short8v pk;
  pk[0] = (short)f2bf(xa.x); pk[1] = (short)f2bf(xa.y);
  pk[2] = (short)f2bf(xa.z); pk[3] = (short)f2bf(xa.w);
  pk[4] = (short)f2bf(xb.x); pk[5] = (short)f2bf(xb.y);
  pk[6] = (short)f2bf(xb.z); pk[7] = (short)f2bf(xb.w);
  *(short8v*)(Xp + (size_t)pos * DIM + lane * 8) = pk;
}

// ============================================================================
// Expert->XCD pinned persistent grouped NT GEMM.  128x128 tile, 4 waves.
// ROUND 10: BK=32 double-buffer, "minimum 2-phase" recipe with HARDENED sync.
// Round-9 race diagnosed (rule #18): bare s_barrier lets the compiler sink
// register-only MFMAs (and their lgkm waits) past the barrier -> a wave can
// arrive with ds_reads outstanding while others overwrite the buffer.
// TILE_SYNC = s_waitcnt vmcnt(0) lgkmcnt(0) (asm, memory) + sched_barrier(0)
//           + s_barrier + sched_barrier(0)  -- ONE sync per BK=32 tile.
// Prefetch STAGE(t+1) issued before COMPUTE(t) -> vmcnt(0) drain overlaps
// compute.  LDS total 32 KiB (2x8KiB A + 2x8KiB B) -> 4 blocks/CU kept.
// ============================================================================
#define TILE_SYNC() do {                                                      \
    asm volatile("s_waitcnt vmcnt(0) lgkmcnt(0)" ::: "memory");               \
    __builtin_amdgcn_sched_barrier(0);                                        \
    __builtin_amdgcn_s_barrier();                                             \
    __builtin_amdgcn_sched_barrier(0);                                        \
  } while (0)
#define MFMA1(d, a, b) d = __builtin_amdgcn_mfma_f32_16x16x32_bf16(a, b, d, 0, 0, 0)

template<int NX, int LOG2NX, int EPI, int KC>
__global__ __launch_bounds__(256, 4) void k_gemm_x(
    const unsigned short* __restrict__ A,   // [2T][K] bf16 rows (expert-grouped)
    const unsigned short* __restrict__ Bt,  // [E][N][K] bf16
    const float* __restrict__ bias,         // [E][N]
    const int* __restrict__ offs,           // [E+1]
    unsigned short* __restrict__ Hout, unsigned short* __restrict__ Ybf,
    int N) {
  __shared__ __align__(16) unsigned short Al[2][128 * 32];
  __shared__ __align__(16) unsigned short Bl[2][128 * 32];

  const int e = blockIdx.x & 7;             // expert == XCD (round-robin)
  const int slot = blockIdx.x >> 3;
  const int nSlots = gridDim.x >> 3;
  const int rowBeg = offs[e], rowEnd = offs[e + 1];
  if (rowBeg >= rowEnd) return;
  const int nMT = (rowEnd - rowBeg + 127) >> 7;
  const int nWork = nMT << LOG2NX;
  const unsigned short* Be = Bt + (size_t)e * N * KC;

  const int tid = threadIdx.x, lane = tid & 63, w = tid >> 6;
  const int wr = w >> 1, wc = w & 1;
  const int fr = lane & 15, fq = lane >> 4;               // fq in 0..3
  const int sR = tid >> 2;                                // staged row 0..63
  const int sCe = ((((tid & 3) << 4) ^ ((sR & 3) << 4)) >> 1);  // swz elem off
  constexpr int NT = KC >> 5;

#define STAGE(pb2, tk) do {                                                   \
    const int _o = (tk) << 6;   /* 32 elems * 2B per K-step */                \
    gload_lds16(aP0 + _o, (char*)&Al[pb2][0] + (w << 10));                    \
    gload_lds16(aP1 + _o, (char*)&Al[pb2][0] + 4096 + (w << 10));             \
    gload_lds16(bP0 + _o, (char*)&Bl[pb2][0] + (w << 10));                    \
    gload_lds16(bP1 + _o, (char*)&Bl[pb2][0] + 4096 + (w << 10));             \
  } while (0)

#define COMPUTE(pb2) do {                                                     \
    short8v av[4], bv[4];                                                     \
    _Pragma("unroll")                                                         \
    for (int m_ = 0; m_ < 4; ++m_) {                                          \
      int row_ = wr * 64 + m_ * 16 + fr;                                      \
      av[m_] = *(const short8v*)((const char*)&Al[pb2][0] + row_ * 64 +       \
                 ((fq << 4) ^ ((row_ & 3) << 4)));                            \
    }                                                                         \
    _Pragma("unroll")                                                         \
    for (int n_ = 0; n_ < 4; ++n_) {                                          \
      int row_ = wc * 64 + n_ * 16 + fr;                                      \
      bv[n_] = *(const short8v*)((const char*)&Bl[pb2][0] + row_ * 64 +       \
                 ((fq << 4) ^ ((row_ & 3) << 4)));                            \
    }                                                                         \
    _Pragma("unroll")                                                         \
    for (int m_ = 0; m_ < 4; ++m_)                                            \
      _Pragma("unroll")                                                       \
      for (int n_ = 0; n_ < 4; ++n_)                                          \
        MFMA1(acc[m_][n_], av[m_], bv[n_]);                                   \
  } while (0)

  for (int idx = slot; idx < nWork; idx += nSlots) {
    const int mt = idx >> LOG2NX;
    const int xb = idx & (NX - 1);
    const int m0 = rowBeg + mt * 128;
    const int n0 = xb * 128;

    // hoisted stage base addresses (byte ptrs incl. pre-swizzled elem offset)
    int ar0 = m0 + sR;       if (ar0 > rowEnd - 1) ar0 = rowEnd - 1;
    int ar1 = m0 + 64 + sR;  if (ar1 > rowEnd - 1) ar1 = rowEnd - 1;
    const char* aP0 = (const char*)(A + (size_t)ar0 * KC + sCe);
    const char* aP1 = (const char*)(A + (size_t)ar1 * KC + sCe);
    const char* bP0 = (const char*)(Be + (size_t)(n0 + sR) * KC + sCe);
    const char* bP1 = (const char*)(Be + (size_t)(n0 + 64 + sR) * KC + sCe);

    f32x4 acc[4][4];
#pragma unroll
    for (int m = 0; m < 4; ++m)
#pragma unroll
      for (int n = 0; n < 4; ++n) acc[m][n] = (f32x4){0.f, 0.f, 0.f, 0.f};

    STAGE(0, 0);                 // prologue: tile 0
    TILE_SYNC();                 // tile 0 fully landed, all waves aligned
    for (int t = 0; t < NT; ++t) {
      const int pb = t & 1;
      if (t + 1 < NT) STAGE(pb ^ 1, t + 1);   // prefetch flies during compute
      COMPUTE(pb);
      TILE_SYNC();               // my gloads landed + my ds_reads done + barrier
    }

    // ---- epilogue ----
#pragma unroll
    for (int m = 0; m < 4; ++m) {
#pragma unroll
      for (int j = 0; j < 4; ++j) {
        int row = m0 + wr * 64 + m * 16 + fq * 4 + j;
        if (row >= rowEnd) continue;
#pragma unroll
        for (int n = 0; n < 4; ++n) {
          int col = n0 + wc * 64 + n * 16 + fr;
          float v = acc[m][n][j] + bias[(size_t)e * N + col];
          if (EPI == 0) Hout[(size_t)row * N + col] = f2bf(gelu_f(v));
          else          Ybf[(size_t)row * N + col] = f2bf(v);
        }
      }
    }
  }
#undef STAGE
#undef COMPUTE
}

// ---- combine: out[t] = g0*Y[p0] + g1*Y[p1] (bf16 reads, f32 math/store) ----
__global__ __launch_bounds__(256) void k_combine(
    const unsigned short* __restrict__ Y, const int* __restrict__ pos_of,
    const float* __restrict__ top_p, float* __restrict__ out) {
  int lane = threadIdx.x & 63;
  int t = blockIdx.x * 4 + (threadIdx.x >> 6);
  int p0 = pos_of[t * 2], p1 = pos_of[t * 2 + 1];
  float g0 = top_p[t * 2], g1 = top_p[t * 2 + 1];
  short8v ya = *(const short8v*)(Y + (size_t)p0 * OUTD + lane * 8);
  short8v yb = *(const short8v*)(Y + (size_t)p1 * OUTD + lane * 8);
  float4 r0, r1;
  r0.x = g0 * bf2f((unsigned short)ya[0]) + g1 * bf2f((unsigned short)yb[0]);
  r0.y = g0 * bf2f((unsigned short)ya[1]) + g1 * bf2f((unsigned short)yb[1]);
  r0.z = g0 * bf2f((unsigned short)ya[2]) + g1 * bf2f((unsigned short)yb[2]);
  r0.w = g0 * bf2f((unsigned short)ya[3]) + g1 * bf2f((unsigned short)yb[3]);
  r1.x = g0 * bf2f((unsigned short)ya[4]) + g1 * bf2f((unsigned short)yb[4]);
  r1.y = g0 * bf2f((unsigned short)ya[5]) + g1 * bf2f((unsigned short)yb[5]);
  r1.z = g0 * bf2f((unsigned short)ya[6]) + g1 * bf2f((unsigned short)yb[6]);
  r1.w = g0 * bf2f((unsigned short)ya[7]) + g1 * bf2f((unsigned short)yb[7]);
  float4* o = (float4*)(out + (size_t)t * OUTD + lane * 8);
  o[0] = r0; o[1] = r1;
}

extern "C" void kernel_launch(void* const* d_in, const int* in_sizes, int n_in,
                              void* d_out, int out_size, void* d_ws, size_t ws_size,
                              hipStream_t stream) {
  const float* x  = (const float*)d_in[0];   // [T, D]
  const float* Wg = (const float*)d_in[1];   // [D, E]
  const float* W1 = (const float*)d_in[2];   // [E, D, H]
  const float* b1 = (const float*)d_in[3];   // [E, H]
  const float* W2 = (const float*)d_in[4];   // [E, H, O]
  const float* b2 = (const float*)d_in[5];   // [E, O]
  float* out = (float*)d_out;                // [T, O]

  char* p = (char*)d_ws;
  auto take = [&](size_t bytes) { char* r = p; p += (bytes + 255) & ~(size_t)255; return r; };
  unsigned short* W1t = (unsigned short*)take((size_t)NE * DIM * HID * 2);   // [E][H][D]
  unsigned short* W2t = (unsigned short*)take((size_t)NE * HID * OUTD * 2);  // [E][O][H]
  unsigned short* Xp  = (unsigned short*)take((size_t)2 * T_TOK * DIM * 2);  // [2T][D]
  unsigned short* Hb  = (unsigned short*)take((size_t)2 * T_TOK * HID * 2);  // [2T][H]
  unsigned short* Yb  = (unsigned short*)take((size_t)2 * T_TOK * OUTD * 2); // [2T][O] bf16
  int* offs   = (int*)take(4096);
  int*   top_e  = (int*)take((size_t)2 * T_TOK * 4);
  float* top_pv = (float*)take((size_t)2 * T_TOK * 4);
  int*   pos_of = (int*)take((size_t)2 * T_TOK * 4);
  int* localRank   = (int*)take((size_t)2 * T_TOK * 4);
  int* blockCounts = (int*)take((size_t)64 * NE * 4);
  int* baseBlk     = (int*)take((size_t)64 * NE * 4);

  const int PLAN_BLOCKS = (2 * T_TOK) / 256;   // 64

  k_trans_all<<<8192, dim3(32, 8), 0, stream>>>(W1, W2, W1t, W2t);
  k_router<<<T_TOK / 4, 256, 0, stream>>>(x, Wg, top_e, top_pv);
  k_plan<<<PLAN_BLOCKS, 256, 0, stream>>>(top_e, localRank, blockCounts);
  k_scan2<<<1, 64, 0, stream>>>(blockCounts, baseBlk, offs, PLAN_BLOCKS);
  k_scatter<<<(2 * T_TOK) / 4, 256, 0, stream>>>(x, top_e, localRank, baseBlk, offs, pos_of, Xp);
  k_gemm_x<8, 3, 0, DIM><<<1024, 256, 0, stream>>>(Xp, W1t, b1, offs, Hb, nullptr, HID);
  k_gemm_x<4, 2, 1, HID><<<512, 256, 0, stream>>>(Hb, W2t, b2, offs, nullptr, Yb, OUTD);
  k_combine<<<T_TOK / 4, 256, 0, stream>>>(Yb, pos_of, top_pv, out);
}

// Round 11
// 137.658 us; speedup vs baseline: 1.0518x; 1.0518x over previous
//
#include <hip/hip_runtime.h>

#define T_TOK 8192
#define DIM   512
#define HID   1024
#define OUTD  512
#define NE    8

typedef __attribute__((ext_vector_type(8))) short short8v;   // 8 bf16 (4 VGPRs)
typedef __attribute__((ext_vector_type(4))) float f32x4;

__device__ __forceinline__ unsigned short f2bf(float f) {
  unsigned int u = __builtin_bit_cast(unsigned int, f);
  u += 0x7fffu + ((u >> 16) & 1u);            // RNE, finite inputs
  return (unsigned short)(u >> 16);
}

__device__ __forceinline__ float bf2f(unsigned short h) {
  unsigned int u = ((unsigned int)h) << 16;
  return __builtin_bit_cast(float, u);
}

__device__ __forceinline__ void gload_lds16(const void* g, void* l) {
  __builtin_amdgcn_global_load_lds(
      (__attribute__((address_space(1))) void*)g,
      (__attribute__((address_space(3))) void*)l, 16, 0, 0);
}

// gelu tanh-approx, exact identity: 0.5v(1+tanh(u)) = v * sigmoid(2u)
__device__ __forceinline__ float gelu_f(float v) {
  const float c0 = 0.7978845608028654f;       // sqrt(2/pi), jax approximate=True
  float u = c0 * (v + 0.044715f * v * v * v);
  return v / (1.0f + __expf(-2.0f * u));
}

// ---- merged transpose+cvt for W1 and W2: [E][R][C] f32 -> [E][C][R] bf16 ----
__global__ __launch_bounds__(256) void k_trans_all(
    const float* __restrict__ W1, const float* __restrict__ W2,
    unsigned short* __restrict__ W1t, unsigned short* __restrict__ W2t) {
  __shared__ float tile[32][33];
  int bid = blockIdx.x;
  int which = bid >> 12;            // 0: W1 (512x1024), 1: W2 (1024x512)
  int r = bid & 4095;
  int e = r >> 9;
  int t = r & 511;
  int R = which ? HID : DIM;
  int C = which ? OUTD : HID;
  int tx, ty;
  if (which == 0) { ty = t >> 5; tx = t & 31; }   // 16 x 32 tiles
  else            { ty = t >> 4; tx = t & 15; }   // 32 x 16 tiles
  const float* inE = (which ? W2 : W1) + (size_t)e * R * C;
  unsigned short* outE = (which ? W2t : W1t) + (size_t)e * R * C;
  int c0 = tx * 32, r0 = ty * 32;
  int x = threadIdx.x, y = threadIdx.y;
#pragma unroll
  for (int i = 0; i < 32; i += 8)
    tile[y + i][x] = inE[(size_t)(r0 + y + i) * C + (c0 + x)];
  __syncthreads();
#pragma unroll
  for (int i = 0; i < 32; i += 8)
    outE[(size_t)(c0 + y + i) * R + (r0 + x)] = f2bf(tile[x][y + i]);
}

// ---- router: one wave per token, f32 logits -> softmax -> top2 (NO atomics) ----
__global__ __launch_bounds__(256) void k_router(
    const float* __restrict__ x, const float* __restrict__ Wg,
    int* __restrict__ top_e, float* __restrict__ top_p) {
  int lane = threadIdx.x & 63;
  int t = blockIdx.x * 4 + (threadIdx.x >> 6);
  const float* xr = x + (size_t)t * DIM;
  int j0 = lane * 8;
  float4 xa = *(const float4*)(xr + j0);
  float4 xb = *(const float4*)(xr + j0 + 4);
  float xl[8] = {xa.x, xa.y, xa.z, xa.w, xb.x, xb.y, xb.z, xb.w};
  float acc[8] = {0.f,0.f,0.f,0.f,0.f,0.f,0.f,0.f};
#pragma unroll
  for (int jj = 0; jj < 8; ++jj) {
    float4 w0 = *(const float4*)(Wg + (size_t)(j0 + jj) * NE);
    float4 w1 = *(const float4*)(Wg + (size_t)(j0 + jj) * NE + 4);
    acc[0] += xl[jj] * w0.x; acc[1] += xl[jj] * w0.y;
    acc[2] += xl[jj] * w0.z; acc[3] += xl[jj] * w0.w;
    acc[4] += xl[jj] * w1.x; acc[5] += xl[jj] * w1.y;
    acc[6] += xl[jj] * w1.z; acc[7] += xl[jj] * w1.w;
  }
#pragma unroll
  for (int off = 32; off >= 1; off >>= 1) {
#pragma unroll
    for (int e2 = 0; e2 < 8; ++e2) acc[e2] += __shfl_xor(acc[e2], off, 64);
  }
  if (lane == 0) {
    float m = acc[0];
#pragma unroll
    for (int e2 = 1; e2 < 8; ++e2) m = fmaxf(m, acc[e2]);
    float p[8]; float s = 0.f;
#pragma unroll
    for (int e2 = 0; e2 < 8; ++e2) { p[e2] = expf(acc[e2] - m); s += p[e2]; }
    float inv = 1.f / s;
    int i0 = 0;
#pragma unroll
    for (int e2 = 1; e2 < 8; ++e2) if (p[e2] > p[i0]) i0 = e2;
    int i1 = (i0 == 0) ? 1 : 0;
#pragma unroll
    for (int e2 = 0; e2 < 8; ++e2) if (e2 != i0 && p[e2] > p[i1]) i1 = e2;
    top_e[t * 2] = i0;  top_e[t * 2 + 1] = i1;
    top_p[t * 2] = p[i0] * inv;  top_p[t * 2 + 1] = p[i1] * inv;
  }
}

// ---- plan: deterministic local ranks via ballot, per-block expert counts ----
__global__ __launch_bounds__(256) void k_plan(
    const int* __restrict__ top_e, int* __restrict__ localRank,
    int* __restrict__ blockCounts) {
  __shared__ int cnt[4][NE];
  __shared__ int wbase[4][NE];
  int tid = threadIdx.x, lane = tid & 63, w = tid >> 6;
  int a = blockIdx.x * 256 + tid;
  int e = top_e[a];
  int rank = 0;
#pragma unroll
  for (int e2 = 0; e2 < NE; ++e2) {
    unsigned long long m = __ballot(e == e2);
    if (e == e2) rank = __popcll(m & ((1ULL << lane) - 1ULL));
    if (lane == 0) cnt[w][e2] = __popcll(m);
  }
  __syncthreads();
  if (tid < NE) {
    int s = 0;
#pragma unroll
    for (int w2 = 0; w2 < 4; ++w2) { wbase[w2][tid] = s; s += cnt[w2][tid]; }
    blockCounts[blockIdx.x * NE + tid] = s;
  }
  __syncthreads();
  localRank[a] = wbase[w][e] + rank;
}

// ---- scan: per-expert prefix over blocks + global expert offsets ----
__global__ void k_scan2(const int* __restrict__ blockCounts, int* __restrict__ baseBlk,
                        int* __restrict__ offs, int nBlocks) {
  __shared__ int tot[NE];
  int tid = threadIdx.x;
  if (tid < NE) {
    int s = 0;
    for (int b = 0; b < nBlocks; ++b) { baseBlk[b * NE + tid] = s; s += blockCounts[b * NE + tid]; }
    tot[tid] = s;
  }
  __syncthreads();
  if (tid == 0) {
    int s = 0;
    for (int e = 0; e < NE; ++e) { offs[e] = s; s += tot[e]; }
    offs[NE] = s;   // == 2*T_TOK
  }
}

// ---- scatter: pos = offs[e] + baseBlk[b][e] + localRank (NO atomics) ----
__global__ __launch_bounds__(256) void k_scatter(
    const float* __restrict__ x, const int* __restrict__ top_e,
    const int* __restrict__ localRank, const int* __restrict__ baseBlk,
    const int* __restrict__ offs, int* __restrict__ pos_of,
    unsigned short* __restrict__ Xp) {
  int lane = threadIdx.x & 63;
  int a = blockIdx.x * 4 + (threadIdx.x >> 6);   // 0..16383
  int t = a >> 1;
  int e = top_e[a];
  int pos = offs[e] + baseBlk[(a >> 8) * NE + e] + localRank[a];
  if (lane == 0) pos_of[a] = pos;
  const float* xr = x + (size_t)t * DIM + lane * 8;
  float4 xa = *(const float4*)xr;
  float4 xb = *(const float4*)(xr + 4);
  short8v pk;
  pk[0] = (short)f2bf(xa.x); pk[1] = (short)f2bf(xa.y);
  pk[2] = (short)f2bf(xa.z); pk[3] = (short)f2bf(xa.w);
  pk[4] = (short)f2bf(xb.x); pk[5] = (short)f2bf(xb.y);
  pk[6] = (short)f2bf(xb.z); pk[7] = (short)f2bf(xb.w);
  *(short8v*)(Xp + (size_t)pos * DIM + lane * 8) = pk;
}

#define MFMA1(d, a, b) d = __builtin_amdgcn_mfma_f32_16x16x32_bf16(a, b, d, 0, 0, 0)

// ============================================================================
// GEMM2 kernel: round-8 exact (verified best for its shape).  128x128 tile,
// BK=64, 4 waves, single-buffer 32 KiB, XCD-pinned, hoisted addresses.
// ============================================================================
template<int NX, int LOG2NX, int EPI>
__global__ __launch_bounds__(256, 4) void k_gemm_x(
    const unsigned short* __restrict__ A, const unsigned short* __restrict__ Bt,
    const float* __restrict__ bias, const int* __restrict__ offs,
    unsigned short* __restrict__ Hout, unsigned short* __restrict__ Ybf,
    int K, int N) {
  __shared__ __align__(16) unsigned short Al[128 * 64];
  __shared__ __align__(16) unsigned short Bl[128 * 64];

  const int e = blockIdx.x & 7;
  const int slot = blockIdx.x >> 3;
  const int nSlots = gridDim.x >> 3;
  const int rowBeg = offs[e], rowEnd = offs[e + 1];
  if (rowBeg >= rowEnd) return;
  const int nMT = (rowEnd - rowBeg + 127) >> 7;
  const int nWork = nMT << LOG2NX;
  const unsigned short* Be = Bt + (size_t)e * N * K;

  const int tid = threadIdx.x, lane = tid & 63, w = tid >> 6;
  const int wr = w >> 1, wc = w & 1;
  const int fr = lane & 15, fq = lane >> 4;
  const int sRow = tid >> 3;                                     // 0..31
  const int sCe = ((((tid & 7) << 4) ^ ((sRow & 7) << 4)) >> 1); // swz elem off
  const int NT = K >> 6;

  for (int idx = slot; idx < nWork; idx += nSlots) {
    const int mt = idx >> LOG2NX;
    const int xb = idx & (NX - 1);
    const int m0 = rowBeg + mt * 128;
    const int n0 = xb * 128;

    const char* aP[4]; const char* bP[4];
#pragma unroll
    for (int c_ = 0; c_ < 4; ++c_) {
      int ar_ = m0 + c_ * 32 + sRow; if (ar_ > rowEnd - 1) ar_ = rowEnd - 1;
      aP[c_] = (const char*)(A + (size_t)ar_ * K + sCe);
      int br_ = n0 + c_ * 32 + sRow;
      bP[c_] = (const char*)(Be + (size_t)br_ * K + sCe);
    }

    f32x4 acc[4][4];
#pragma unroll
    for (int m = 0; m < 4; ++m)
#pragma unroll
      for (int n = 0; n < 4; ++n) acc[m][n] = (f32x4){0.f, 0.f, 0.f, 0.f};

    for (int t = 0; t < NT; ++t) {
      const int tOff = t << 7;
#pragma unroll
      for (int c_ = 0; c_ < 4; ++c_)
        gload_lds16(aP[c_] + tOff, (char*)&Al[0] + c_ * 4096 + (w << 10));
#pragma unroll
      for (int c_ = 0; c_ < 4; ++c_)
        gload_lds16(bP[c_] + tOff, (char*)&Bl[0] + c_ * 4096 + (w << 10));
      __syncthreads();
#pragma unroll
      for (int kk = 0; kk < 2; ++kk) {
        short8v av[4], bv[4];
#pragma unroll
        for (int m = 0; m < 4; ++m) {
          int row_ = wr * 64 + m * 16 + fr;
          av[m] = *(const short8v*)((const char*)&Al[0] + row_ * 128 +
                    (((kk << 6) + (fq << 4)) ^ ((fr & 7) << 4)));
        }
#pragma unroll
        for (int n = 0; n < 4; ++n) {
          int row_ = wc * 64 + n * 16 + fr;
          bv[n] = *(const short8v*)((const char*)&Bl[0] + row_ * 128 +
                    (((kk << 6) + (fq << 4)) ^ ((fr & 7) << 4)));
        }
#pragma unroll
        for (int m = 0; m < 4; ++m)
#pragma unroll
          for (int n = 0; n < 4; ++n)
            MFMA1(acc[m][n], av[m], bv[n]);
      }
      __syncthreads();
    }

#pragma unroll
    for (int m = 0; m < 4; ++m) {
#pragma unroll
      for (int j = 0; j < 4; ++j) {
        int row = m0 + wr * 64 + m * 16 + fq * 4 + j;
        if (row >= rowEnd) continue;
#pragma unroll
        for (int n = 0; n < 4; ++n) {
          int col = n0 + wc * 64 + n * 16 + fr;
          float v = acc[m][n][j] + bias[(size_t)e * N + col];
          if (EPI == 0) Hout[(size_t)row * N + col] = f2bf(gelu_f(v));
          else          Ybf[(size_t)row * N + col] = f2bf(v);
        }
      }
    }
  }
}

// ============================================================================
// GEMM1 kernel: WIDE 256x128 tile, BK=64, 8 waves (4M x 2N), single-buffer
// 48 KiB LDS (A 32K + B 16K).  Same 2-barrier loop / swizzle / pinning as
// round 8 -- only compute-per-drain doubled (256 MFMA per K-step per block).
// ============================================================================
template<int NX, int LOG2NX, int EPI>
__global__ __launch_bounds__(512, 4) void k_gemm_w(
    const unsigned short* __restrict__ A, const unsigned short* __restrict__ Bt,
    const float* __restrict__ bias, const int* __restrict__ offs,
    unsigned short* __restrict__ Hout, unsigned short* __restrict__ Ybf,
    int K, int N) {
  __shared__ __align__(16) unsigned short Al[256 * 64];   // 32 KiB
  __shared__ __align__(16) unsigned short Bl[128 * 64];   // 16 KiB

  const int e = blockIdx.x & 7;
  const int slot = blockIdx.x >> 3;
  const int nSlots = gridDim.x >> 3;
  const int rowBeg = offs[e], rowEnd = offs[e + 1];
  if (rowBeg >= rowEnd) return;
  const int nMT = (rowEnd - rowBeg + 255) >> 8;
  const int nWork = nMT << LOG2NX;
  const unsigned short* Be = Bt + (size_t)e * N * K;

  const int tid = threadIdx.x, lane = tid & 63, w = tid >> 6;   // w 0..7
  const int wm = w >> 1, wn = w & 1;                            // 4M x 2N
  const int fr = lane & 15, fq = lane >> 4;
  const int sRow = tid >> 3;                                     // 0..63
  const int sCe = ((((tid & 7) << 4) ^ ((sRow & 7) << 4)) >> 1); // swz elem off
  const int NT = K >> 6;

  for (int idx = slot; idx < nWork; idx += nSlots) {
    const int mt = idx >> LOG2NX;
    const int xb = idx & (NX - 1);
    const int m0 = rowBeg + mt * 256;
    const int n0 = xb * 128;

    // hoisted stage bases: A 4 groups of 64 rows; B 2 groups of 64 rows
    const char* aP[4]; const char* bP[2];
#pragma unroll
    for (int c_ = 0; c_ < 4; ++c_) {
      int ar_ = m0 + c_ * 64 + sRow; if (ar_ > rowEnd - 1) ar_ = rowEnd - 1;
      aP[c_] = (const char*)(A + (size_t)ar_ * K + sCe);
    }
#pragma unroll
    for (int c_ = 0; c_ < 2; ++c_) {
      int br_ = n0 + c_ * 64 + sRow;
      bP[c_] = (const char*)(Be + (size_t)br_ * K + sCe);
    }

    f32x4 acc[4][4];
#pragma unroll
    for (int m = 0; m < 4; ++m)
#pragma unroll
      for (int n = 0; n < 4; ++n) acc[m][n] = (f32x4){0.f, 0.f, 0.f, 0.f};

    for (int t = 0; t < NT; ++t) {
      const int tOff = t << 7;
#pragma unroll
      for (int c_ = 0; c_ < 4; ++c_)
        gload_lds16(aP[c_] + tOff, (char*)&Al[0] + c_ * 8192 + (w << 10));
#pragma unroll
      for (int c_ = 0; c_ < 2; ++c_)
        gload_lds16(bP[c_] + tOff, (char*)&Bl[0] + c_ * 8192 + (w << 10));
      __syncthreads();
#pragma unroll
      for (int kk = 0; kk < 2; ++kk) {
        short8v av[4], bv[4];
#pragma unroll
        for (int m = 0; m < 4; ++m) {
          int row_ = wm * 64 + m * 16 + fr;                     // 0..255
          av[m] = *(const short8v*)((const char*)&Al[0] + row_ * 128 +
                    (((kk << 6) + (fq << 4)) ^ ((fr & 7) << 4)));
        }
#pragma unroll
        for (int n = 0; n < 4; ++n) {
          int row_ = wn * 64 + n * 16 + fr;                     // 0..127
          bv[n] = *(const short8v*)((const char*)&Bl[0] + row_ * 128 +
                    (((kk << 6) + (fq << 4)) ^ ((fr & 7) << 4)));
        }
#pragma unroll
        for (int m = 0; m < 4; ++m)
#pragma unroll
          for (int n = 0; n < 4; ++n)
            MFMA1(acc[m][n], av[m], bv[n]);
      }
      __syncthreads();
    }

#pragma unroll
    for (int m = 0; m < 4; ++m) {
#pragma unroll
      for (int j = 0; j < 4; ++j) {
        int row = m0 + wm * 64 + m * 16 + fq * 4 + j;
        if (row >= rowEnd) continue;
#pragma unroll
        for (int n = 0; n < 4; ++n) {
          int col = n0 + wn * 64 + n * 16 + fr;
          float v = acc[m][n][j] + bias[(size_t)e * N + col];
          if (EPI == 0) Hout[(size_t)row * N + col] = f2bf(gelu_f(v));
          else          Ybf[(size_t)row * N + col] = f2bf(v);
        }
      }
    }
  }
}

// ---- combine: out[t] = g0*Y[p0] + g1*Y[p1] (bf16 reads, f32 math/store) ----
__global__ __launch_bounds__(256) void k_combine(
    const unsigned short* __restrict__ Y, const int* __restrict__ pos_of,
    const float* __restrict__ top_p, float* __restrict__ out) {
  int lane = threadIdx.x & 63;
  int t = blockIdx.x * 4 + (threadIdx.x >> 6);
  int p0 = pos_of[t * 2], p1 = pos_of[t * 2 + 1];
  float g0 = top_p[t * 2], g1 = top_p[t * 2 + 1];
  short8v ya = *(const short8v*)(Y + (size_t)p0 * OUTD + lane * 8);
  short8v yb = *(const short8v*)(Y + (size_t)p1 * OUTD + lane * 8);
  float4 r0, r1;
  r0.x = g0 * bf2f((unsigned short)ya[0]) + g1 * bf2f((unsigned short)yb[0]);
  r0.y = g0 * bf2f((unsigned short)ya[1]) + g1 * bf2f((unsigned short)yb[1]);
  r0.z = g0 * bf2f((unsigned short)ya[2]) + g1 * bf2f((unsigned short)yb[2]);
  r0.w = g0 * bf2f((unsigned short)ya[3]) + g1 * bf2f((unsigned short)yb[3]);
  r1.x = g0 * bf2f((unsigned short)ya[4]) + g1 * bf2f((unsigned short)yb[4]);
  r1.y = g0 * bf2f((unsigned short)ya[5]) + g1 * bf2f((unsigned short)yb[5]);
  r1.z = g0 * bf2f((unsigned short)ya[6]) + g1 * bf2f((unsigned short)yb[6]);
  r1.w = g0 * bf2f((unsigned short)ya[7]) + g1 * bf2f((unsigned short)yb[7]);
  float4* o = (float4*)(out + (size_t)t * OUTD + lane * 8);
  o[0] = r0; o[1] = r1;
}

extern "C" void kernel_launch(void* const* d_in, const int* in_sizes, int n_in,
                              void* d_out, int out_size, void* d_ws, size_t ws_size,
                              hipStream_t stream) {
  const float* x  = (const float*)d_in[0];   // [T, D]
  const float* Wg = (const float*)d_in[1];   // [D, E]
  const float* W1 = (const float*)d_in[2];   // [E, D, H]
  const float* b1 = (const float*)d_in[3];   // [E, H]
  const float* W2 = (const float*)d_in[4];   // [E, H, O]
  const float* b2 = (const float*)d_in[5];   // [E, O]
  float* out = (float*)d_out;                // [T, O]

  char* p = (char*)d_ws;
  auto take = [&](size_t bytes) { char* r = p; p += (bytes + 255) & ~(size_t)255; return r; };
  unsigned short* W1t = (unsigned short*)take((size_t)NE * DIM * HID * 2);   // [E][H][D]
  unsigned short* W2t = (unsigned short*)take((size_t)NE * HID * OUTD * 2);  // [E][O][H]
  unsigned short* Xp  = (unsigned short*)take((size_t)2 * T_TOK * DIM * 2);  // [2T][D]
  unsigned short* Hb  = (unsigned short*)take((size_t)2 * T_TOK * HID * 2);  // [2T][H]
  unsigned short* Yb  = (unsigned short*)take((size_t)2 * T_TOK * OUTD * 2); // [2T][O] bf16
  int* offs   = (int*)take(4096);
  int*   top_e  = (int*)take((size_t)2 * T_TOK * 4);
  float* top_pv = (float*)take((size_t)2 * T_TOK * 4);
  int*   pos_of = (int*)take((size_t)2 * T_TOK * 4);
  int* localRank   = (int*)take((size_t)2 * T_TOK * 4);
  int* blockCounts = (int*)take((size_t)64 * NE * 4);
  int* baseBlk     = (int*)take((size_t)64 * NE * 4);

  const int PLAN_BLOCKS = (2 * T_TOK) / 256;   // 64

  k_trans_all<<<8192, dim3(32, 8), 0, stream>>>(W1, W2, W1t, W2t);
  k_router<<<T_TOK / 4, 256, 0, stream>>>(x, Wg, top_e, top_pv);
  k_plan<<<PLAN_BLOCKS, 256, 0, stream>>>(top_e, localRank, blockCounts);
  k_scan2<<<1, 64, 0, stream>>>(blockCounts, baseBlk, offs, PLAN_BLOCKS);
  k_scatter<<<(2 * T_TOK) / 4, 256, 0, stream>>>(x, top_e, localRank, baseBlk, offs, pos_of, Xp);
  k_gemm_w<8, 3, 0><<<1024, 512, 0, stream>>>(Xp, W1t, b1, offs, Hb, nullptr, DIM, HID);
  k_gemm_x<4, 2, 1><<<512, 256, 0, stream>>>(Hb, W2t, b2, offs, nullptr, Yb, HID, OUTD);
  k_combine<<<T_TOK / 4, 256, 0, stream>>>(Yb, pos_of, top_pv, out);
}

// Round 12
// 127.435 us; speedup vs baseline: 1.1361x; 1.0802x over previous
//
#include <hip/hip_runtime.h>

#define T_TOK 8192
#define DIM   512
#define HID   1024
#define OUTD  512
#define NE    8

typedef __attribute__((ext_vector_type(8))) short short8v;   // 8 bf16 (4 VGPRs)
typedef __attribute__((ext_vector_type(4))) float f32x4;

__device__ __forceinline__ unsigned short f2bf(float f) {
  unsigned int u = __builtin_bit_cast(unsigned int, f);
  u += 0x7fffu + ((u >> 16) & 1u);            // RNE, finite inputs
  return (unsigned short)(u >> 16);
}

__device__ __forceinline__ float bf2f(unsigned short h) {
  unsigned int u = ((unsigned int)h) << 16;
  return __builtin_bit_cast(float, u);
}

__device__ __forceinline__ void gload_lds16(const void* g, void* l) {
  __builtin_amdgcn_global_load_lds(
      (__attribute__((address_space(1))) void*)g,
      (__attribute__((address_space(3))) void*)l, 16, 0, 0);
}

// gelu tanh-approx, exact identity: 0.5v(1+tanh(u)) = v * sigmoid(2u)
__device__ __forceinline__ float gelu_f(float v) {
  const float c0 = 0.7978845608028654f;       // sqrt(2/pi), jax approximate=True
  float u = c0 * (v + 0.044715f * v * v * v);
  return v / (1.0f + __expf(-2.0f * u));
}

// ============================================================================
// prep: fused {W1,W2 transpose+cvt} (blocks 0..8191) + {router} (8192..10239).
// Independent memory-bound phases overlap in one launch.
// ============================================================================
__global__ __launch_bounds__(256) void k_prep(
    const float* __restrict__ W1, const float* __restrict__ W2,
    unsigned short* __restrict__ W1t, unsigned short* __restrict__ W2t,
    const float* __restrict__ x, const float* __restrict__ Wg,
    int* __restrict__ top_e, float* __restrict__ top_p) {
  int bid = blockIdx.x;
  int tid = threadIdx.x;
  if (bid < 8192) {
    // ---- transpose+cvt: [E][R][C] f32 -> [E][C][R] bf16 ----
    __shared__ float tile[32][33];
    int which = bid >> 12;            // 0: W1 (512x1024), 1: W2 (1024x512)
    int r = bid & 4095;
    int e = r >> 9;
    int t = r & 511;
    int R = which ? HID : DIM;
    int C = which ? OUTD : HID;
    int tx, ty;
    if (which == 0) { ty = t >> 5; tx = t & 31; }   // 16 x 32 tiles
    else            { ty = t >> 4; tx = t & 15; }   // 32 x 16 tiles
    const float* inE = (which ? W2 : W1) + (size_t)e * R * C;
    unsigned short* outE = (which ? W2t : W1t) + (size_t)e * R * C;
    int c0 = tx * 32, r0 = ty * 32;
    int xx = tid & 31, yy = tid >> 5;
#pragma unroll
    for (int i = 0; i < 32; i += 8)
      tile[yy + i][xx] = inE[(size_t)(r0 + yy + i) * C + (c0 + xx)];
    __syncthreads();
#pragma unroll
    for (int i = 0; i < 32; i += 8)
      outE[(size_t)(c0 + yy + i) * R + (r0 + xx)] = f2bf(tile[xx][yy + i]);
  } else {
    // ---- router: one wave per token ----
    int lane = tid & 63;
    int t = (bid - 8192) * 4 + (tid >> 6);
    const float* xr = x + (size_t)t * DIM;
    int j0 = lane * 8;
    float4 xa = *(const float4*)(xr + j0);
    float4 xb = *(const float4*)(xr + j0 + 4);
    float xl[8] = {xa.x, xa.y, xa.z, xa.w, xb.x, xb.y, xb.z, xb.w};
    float acc[8] = {0.f,0.f,0.f,0.f,0.f,0.f,0.f,0.f};
#pragma unroll
    for (int jj = 0; jj < 8; ++jj) {
      float4 w0 = *(const float4*)(Wg + (size_t)(j0 + jj) * NE);
      float4 w1 = *(const float4*)(Wg + (size_t)(j0 + jj) * NE + 4);
      acc[0] += xl[jj] * w0.x; acc[1] += xl[jj] * w0.y;
      acc[2] += xl[jj] * w0.z; acc[3] += xl[jj] * w0.w;
      acc[4] += xl[jj] * w1.x; acc[5] += xl[jj] * w1.y;
      acc[6] += xl[jj] * w1.z; acc[7] += xl[jj] * w1.w;
    }
#pragma unroll
    for (int off = 32; off >= 1; off >>= 1) {
#pragma unroll
      for (int e2 = 0; e2 < 8; ++e2) acc[e2] += __shfl_xor(acc[e2], off, 64);
    }
    if (lane == 0) {
      float m = acc[0];
#pragma unroll
      for (int e2 = 1; e2 < 8; ++e2) m = fmaxf(m, acc[e2]);
      float p[8]; float s = 0.f;
#pragma unroll
      for (int e2 = 0; e2 < 8; ++e2) { p[e2] = expf(acc[e2] - m); s += p[e2]; }
      float inv = 1.f / s;
      int i0 = 0;
#pragma unroll
      for (int e2 = 1; e2 < 8; ++e2) if (p[e2] > p[i0]) i0 = e2;
      int i1 = (i0 == 0) ? 1 : 0;
#pragma unroll
      for (int e2 = 0; e2 < 8; ++e2) if (e2 != i0 && p[e2] > p[i1]) i1 = e2;
      top_e[t * 2] = i0;  top_e[t * 2 + 1] = i1;
      top_p[t * 2] = p[i0] * inv;  top_p[t * 2 + 1] = p[i1] * inv;
    }
  }
}

// ---- plan: deterministic local ranks via ballot, per-block expert counts ----
__global__ __launch_bounds__(256) void k_plan(
    const int* __restrict__ top_e, int* __restrict__ localRank,
    int* __restrict__ blockCounts) {
  __shared__ int cnt[4][NE];
  __shared__ int wbase[4][NE];
  int tid = threadIdx.x, lane = tid & 63, w = tid >> 6;
  int a = blockIdx.x * 256 + tid;
  int e = top_e[a];
  int rank = 0;
#pragma unroll
  for (int e2 = 0; e2 < NE; ++e2) {
    unsigned long long m = __ballot(e == e2);
    if (e == e2) rank = __popcll(m & ((1ULL << lane) - 1ULL));
    if (lane == 0) cnt[w][e2] = __popcll(m);
  }
  __syncthreads();
  if (tid < NE) {
    int s = 0;
#pragma unroll
    for (int w2 = 0; w2 < 4; ++w2) { wbase[w2][tid] = s; s += cnt[w2][tid]; }
    blockCounts[blockIdx.x * NE + tid] = s;
  }
  __syncthreads();
  localRank[a] = wbase[w][e] + rank;
}

// ============================================================================
// scatter with INLINE SCAN (k_scan2 launch removed): each block recomputes the
// per-expert prefix over the 64 plan-groups (8 threads x 64 iters, L2-cached).
// Block 0 publishes offs[] for the GEMMs.  pos deterministic, no atomics.
// ============================================================================
__global__ __launch_bounds__(256) void k_scatter(
    const float* __restrict__ x, const int* __restrict__ top_e,
    const int* __restrict__ localRank, const int* __restrict__ blockCounts,
    int* __restrict__ offs, int* __restrict__ pos_of,
    unsigned short* __restrict__ Xp) {
  __shared__ int sBase[NE];   // within-expert offset of this block's group
  __shared__ int sTot[NE];
  __shared__ int sOffs[NE];
  int tid = threadIdx.x;
  int g = blockIdx.x >> 6;    // plan-group (256 assignments) of this block
  if (tid < NE) {
    int pre = 0, tot = 0;
    for (int b = 0; b < 64; ++b) {
      int c = blockCounts[b * NE + tid];
      if (b < g) pre += c;
      tot += c;
    }
    sBase[tid] = pre; sTot[tid] = tot;
  }
  __syncthreads();
  if (tid == 0) {
    int s = 0;
#pragma unroll
    for (int e = 0; e < NE; ++e) { sOffs[e] = s; s += sTot[e]; }
    if (blockIdx.x == 0) {
      for (int e = 0; e < NE; ++e) offs[e] = sOffs[e];
      offs[NE] = s;
    }
  }
  __syncthreads();
  int lane = tid & 63;
  int a = blockIdx.x * 4 + (tid >> 6);   // 0..16383
  int t = a >> 1;
  int e = top_e[a];
  int pos = sOffs[e] + sBase[e] + localRank[a];
  if (lane == 0) pos_of[a] = pos;
  const float* xr = x + (size_t)t * DIM + lane * 8;
  float4 xa = *(const float4*)xr;
  float4 xb = *(const float4*)(xr + 4);
  short8v pk;
  pk[0] = (short)f2bf(xa.x); pk[1] = (short)f2bf(xa.y);
  pk[2] = (short)f2bf(xa.z); pk[3] = (short)f2bf(xa.w);
  pk[4] = (short)f2bf(xb.x); pk[5] = (short)f2bf(xb.y);
  pk[6] = (short)f2bf(xb.z); pk[7] = (short)f2bf(xb.w);
  *(short8v*)(Xp + (size_t)pos * DIM + lane * 8) = pk;
}

#define MFMA1(d, a, b) d = __builtin_amdgcn_mfma_f32_16x16x32_bf16(a, b, d, 0, 0, 0)

// ============================================================================
// GEMM1: WIDE 256x128 tile, BK=64, 8 waves, single-buffer 48 KiB (round-11
// verified).  XCD-pinned, hoisted addresses, XOR swizzle (0 conflicts).
// ============================================================================
template<int NX, int LOG2NX>
__global__ __launch_bounds__(512, 4) void k_gemm_w(
    const unsigned short* __restrict__ A, const unsigned short* __restrict__ Bt,
    const float* __restrict__ bias, const int* __restrict__ offs,
    unsigned short* __restrict__ Hout, int K, int N) {
  __shared__ __align__(16) unsigned short Al[256 * 64];   // 32 KiB
  __shared__ __align__(16) unsigned short Bl[128 * 64];   // 16 KiB

  const int e = blockIdx.x & 7;
  const int slot = blockIdx.x >> 3;
  const int nSlots = gridDim.x >> 3;
  const int rowBeg = offs[e], rowEnd = offs[e + 1];
  if (rowBeg >= rowEnd) return;
  const int nMT = (rowEnd - rowBeg + 255) >> 8;
  const int nWork = nMT << LOG2NX;
  const unsigned short* Be = Bt + (size_t)e * N * K;

  const int tid = threadIdx.x, lane = tid & 63, w = tid >> 6;   // w 0..7
  const int wm = w >> 1, wn = w & 1;                            // 4M x 2N
  const int fr = lane & 15, fq = lane >> 4;
  const int sRow = tid >> 3;                                     // 0..63
  const int sCe = ((((tid & 7) << 4) ^ ((sRow & 7) << 4)) >> 1); // swz elem off
  const int NT = K >> 6;

  for (int idx = slot; idx < nWork; idx += nSlots) {
    const int mt = idx >> LOG2NX;
    const int xb = idx & (NX - 1);
    const int m0 = rowBeg + mt * 256;
    const int n0 = xb * 128;

    const char* aP[4]; const char* bP[2];
#pragma unroll
    for (int c_ = 0; c_ < 4; ++c_) {
      int ar_ = m0 + c_ * 64 + sRow; if (ar_ > rowEnd - 1) ar_ = rowEnd - 1;
      aP[c_] = (const char*)(A + (size_t)ar_ * K + sCe);
    }
#pragma unroll
    for (int c_ = 0; c_ < 2; ++c_) {
      int br_ = n0 + c_ * 64 + sRow;
      bP[c_] = (const char*)(Be + (size_t)br_ * K + sCe);
    }

    f32x4 acc[4][4];
#pragma unroll
    for (int m = 0; m < 4; ++m)
#pragma unroll
      for (int n = 0; n < 4; ++n) acc[m][n] = (f32x4){0.f, 0.f, 0.f, 0.f};

    for (int t = 0; t < NT; ++t) {
      const int tOff = t << 7;
#pragma unroll
      for (int c_ = 0; c_ < 4; ++c_)
        gload_lds16(aP[c_] + tOff, (char*)&Al[0] + c_ * 8192 + (w << 10));
#pragma unroll
      for (int c_ = 0; c_ < 2; ++c_)
        gload_lds16(bP[c_] + tOff, (char*)&Bl[0] + c_ * 8192 + (w << 10));
      __syncthreads();
#pragma unroll
      for (int kk = 0; kk < 2; ++kk) {
        short8v av[4], bv[4];
#pragma unroll
        for (int m = 0; m < 4; ++m) {
          int row_ = wm * 64 + m * 16 + fr;                     // 0..255
          av[m] = *(const short8v*)((const char*)&Al[0] + row_ * 128 +
                    (((kk << 6) + (fq << 4)) ^ ((fr & 7) << 4)));
        }
#pragma unroll
        for (int n = 0; n < 4; ++n) {
          int row_ = wn * 64 + n * 16 + fr;                     // 0..127
          bv[n] = *(const short8v*)((const char*)&Bl[0] + row_ * 128 +
                    (((kk << 6) + (fq << 4)) ^ ((fr & 7) << 4)));
        }
#pragma unroll
        for (int m = 0; m < 4; ++m)
#pragma unroll
          for (int n = 0; n < 4; ++n)
            MFMA1(acc[m][n], av[m], bv[n]);
      }
      __syncthreads();
    }

#pragma unroll
    for (int m = 0; m < 4; ++m) {
#pragma unroll
      for (int j = 0; j < 4; ++j) {
        int row = m0 + wm * 64 + m * 16 + fq * 4 + j;
        if (row >= rowEnd) continue;
#pragma unroll
        for (int n = 0; n < 4; ++n) {
          int col = n0 + wn * 64 + n * 16 + fr;
          float v = acc[m][n][j] + bias[(size_t)e * N + col];
          Hout[(size_t)row * N + col] = f2bf(gelu_f(v));
        }
      }
    }
  }
}

// ============================================================================
// GEMM2: 128x128 tile, BK=128 (NT=8, half the syncs of round 8), 4 waves,
// single-buffer 64 KiB LDS.  Grid already caps busy blocks at 2/CU, so the
// larger LDS costs nothing.  Same XOR swizzle at 256B-row granularity
// (row&7 == sRow&7 invariant).  64 MFMA per K-step per wave-tile.
// ============================================================================
template<int NX, int LOG2NX>
__global__ __launch_bounds__(256, 2) void k_gemm_y(
    const unsigned short* __restrict__ A,   // Hb [2T][K] bf16
    const unsigned short* __restrict__ Bt,  // [E][N][K] bf16
    const float* __restrict__ bias, const int* __restrict__ offs,
    unsigned short* __restrict__ Ybf, int K, int N) {
  __shared__ __align__(16) unsigned short Al[128 * 128];  // 32 KiB
  __shared__ __align__(16) unsigned short Bl[128 * 128];  // 32 KiB

  const int e = blockIdx.x & 7;
  const int slot = blockIdx.x >> 3;
  const int nSlots = gridDim.x >> 3;
  const int rowBeg = offs[e], rowEnd = offs[e + 1];
  if (rowBeg >= rowEnd) return;
  const int nMT = (rowEnd - rowBeg + 127) >> 7;
  const int nWork = nMT << LOG2NX;
  const unsigned short* Be = Bt + (size_t)e * N * K;

  const int tid = threadIdx.x, lane = tid & 63, w = tid >> 6;
  const int wr = w >> 1, wc = w & 1;
  const int fr = lane & 15, fq = lane >> 4;
  const int sRow = tid >> 4;                                // 0..15
  const int sCb = (((tid & 15) << 4) ^ ((sRow & 7) << 4));  // byte off in 256B row
  const int NT = K >> 7;                                    // 8

  for (int idx = slot; idx < nWork; idx += nSlots) {
    const int mt = idx >> LOG2NX;
    const int xb = idx & (NX - 1);
    const int m0 = rowBeg + mt * 128;
    const int n0 = xb * 128;

    // hoisted bases: A needs per-group clamp (8 ptrs); B one base + const strides
    const char* aP[8];
#pragma unroll
    for (int c_ = 0; c_ < 8; ++c_) {
      int ar_ = m0 + c_ * 16 + sRow; if (ar_ > rowEnd - 1) ar_ = rowEnd - 1;
      aP[c_] = (const char*)(A + (size_t)ar_ * K) + sCb;
    }
    const char* bP0 = (const char*)(Be + (size_t)(n0 + sRow) * K) + sCb;
    const int bStride = 16 * K * 2;                         // 16 rows

    f32x4 acc[4][4];
#pragma unroll
    for (int m = 0; m < 4; ++m)
#pragma unroll
      for (int n = 0; n < 4; ++n) acc[m][n] = (f32x4){0.f, 0.f, 0.f, 0.f};

    for (int t = 0; t < NT; ++t) {
      const int tOff = t << 8;                              // 256 B per K-step
#pragma unroll
      for (int c_ = 0; c_ < 8; ++c_)
        gload_lds16(aP[c_] + tOff, (char*)&Al[0] + c_ * 4096 + (tid << 4));
#pragma unroll
      for (int c_ = 0; c_ < 8; ++c_)
        gload_lds16(bP0 + c_ * bStride + tOff, (char*)&Bl[0] + c_ * 4096 + (tid << 4));
      __syncthreads();
#pragma unroll
      for (int kk = 0; kk < 4; ++kk) {
        short8v av[4], bv[4];
#pragma unroll
        for (int m = 0; m < 4; ++m) {
          int row_ = wr * 64 + m * 16 + fr;
          av[m] = *(const short8v*)((const char*)&Al[0] + row_ * 256 +
                    (((kk << 6) + (fq << 4)) ^ ((fr & 7) << 4)));
        }
#pragma unroll
        for (int n = 0; n < 4; ++n) {
          int row_ = wc * 64 + n * 16 + fr;
          bv[n] = *(const short8v*)((const char*)&Bl[0] + row_ * 256 +
                    (((kk << 6) + (fq << 4)) ^ ((fr & 7) << 4)));
        }
#pragma unroll
        for (int m = 0; m < 4; ++m)
#pragma unroll
          for (int n = 0; n < 4; ++n)
            MFMA1(acc[m][n], av[m], bv[n]);
      }
      __syncthreads();
    }

#pragma unroll
    for (int m = 0; m < 4; ++m) {
#pragma unroll
      for (int j = 0; j < 4; ++j) {
        int row = m0 + wr * 64 + m * 16 + fq * 4 + j;
        if (row >= rowEnd) continue;
#pragma unroll
        for (int n = 0; n < 4; ++n) {
          int col = n0 + wc * 64 + n * 16 + fr;
          float v = acc[m][n][j] + bias[(size_t)e * N + col];
          Ybf[(size_t)row * N + col] = f2bf(v);
        }
      }
    }
  }
}

// ---- combine: out[t] = g0*Y[p0] + g1*Y[p1] (bf16 reads, f32 math/store) ----
__global__ __launch_bounds__(256) void k_combine(
    const unsigned short* __restrict__ Y, const int* __restrict__ pos_of,
    const float* __restrict__ top_p, float* __restrict__ out) {
  int lane = threadIdx.x & 63;
  int t = blockIdx.x * 4 + (threadIdx.x >> 6);
  int p0 = pos_of[t * 2], p1 = pos_of[t * 2 + 1];
  float g0 = top_p[t * 2], g1 = top_p[t * 2 + 1];
  short8v ya = *(const short8v*)(Y + (size_t)p0 * OUTD + lane * 8);
  short8v yb = *(const short8v*)(Y + (size_t)p1 * OUTD + lane * 8);
  float4 r0, r1;
  r0.x = g0 * bf2f((unsigned short)ya[0]) + g1 * bf2f((unsigned short)yb[0]);
  r0.y = g0 * bf2f((unsigned short)ya[1]) + g1 * bf2f((unsigned short)yb[1]);
  r0.z = g0 * bf2f((unsigned short)ya[2]) + g1 * bf2f((unsigned short)yb[2]);
  r0.w = g0 * bf2f((unsigned short)ya[3]) + g1 * bf2f((unsigned short)yb[3]);
  r1.x = g0 * bf2f((unsigned short)ya[4]) + g1 * bf2f((unsigned short)yb[4]);
  r1.y = g0 * bf2f((unsigned short)ya[5]) + g1 * bf2f((unsigned short)yb[5]);
  r1.z = g0 * bf2f((unsigned short)ya[6]) + g1 * bf2f((unsigned short)yb[6]);
  r1.w = g0 * bf2f((unsigned short)ya[7]) + g1 * bf2f((unsigned short)yb[7]);
  float4* o = (float4*)(out + (size_t)t * OUTD + lane * 8);
  o[0] = r0; o[1] = r1;
}

extern "C" void kernel_launch(void* const* d_in, const int* in_sizes, int n_in,
                              void* d_out, int out_size, void* d_ws, size_t ws_size,
                              hipStream_t stream) {
  const float* x  = (const float*)d_in[0];   // [T, D]
  const float* Wg = (const float*)d_in[1];   // [D, E]
  const float* W1 = (const float*)d_in[2];   // [E, D, H]
  const float* b1 = (const float*)d_in[3];   // [E, H]
  const float* W2 = (const float*)d_in[4];   // [E, H, O]
  const float* b2 = (const float*)d_in[5];   // [E, O]
  float* out = (float*)d_out;                // [T, O]

  char* p = (char*)d_ws;
  auto take = [&](size_t bytes) { char* r = p; p += (bytes + 255) & ~(size_t)255; return r; };
  unsigned short* W1t = (unsigned short*)take((size_t)NE * DIM * HID * 2);   // [E][H][D]
  unsigned short* W2t = (unsigned short*)take((size_t)NE * HID * OUTD * 2);  // [E][O][H]
  unsigned short* Xp  = (unsigned short*)take((size_t)2 * T_TOK * DIM * 2);  // [2T][D]
  unsigned short* Hb  = (unsigned short*)take((size_t)2 * T_TOK * HID * 2);  // [2T][H]
  unsigned short* Yb  = (unsigned short*)take((size_t)2 * T_TOK * OUTD * 2); // [2T][O] bf16
  int* offs   = (int*)take(4096);
  int*   top_e  = (int*)take((size_t)2 * T_TOK * 4);
  float* top_pv = (float*)take((size_t)2 * T_TOK * 4);
  int*   pos_of = (int*)take((size_t)2 * T_TOK * 4);
  int* localRank   = (int*)take((size_t)2 * T_TOK * 4);
  int* blockCounts = (int*)take((size_t)64 * NE * 4);

  const int PLAN_BLOCKS = (2 * T_TOK) / 256;   // 64

  k_prep<<<8192 + 2048, 256, 0, stream>>>(W1, W2, W1t, W2t, x, Wg, top_e, top_pv);
  k_plan<<<PLAN_BLOCKS, 256, 0, stream>>>(top_e, localRank, blockCounts);
  k_scatter<<<(2 * T_TOK) / 4, 256, 0, stream>>>(x, top_e, localRank, blockCounts,
                                                 offs, pos_of, Xp);
  k_gemm_w<8, 3><<<1024, 512, 0, stream>>>(Xp, W1t, b1, offs, Hb, DIM, HID);
  k_gemm_y<4, 2><<<512, 256, 0, stream>>>(Hb, W2t, b2, offs, Yb, HID, OUTD);
  k_combine<<<T_TOK / 4, 256, 0, stream>>>(Yb, pos_of, top_pv, out);
}

// Round 13
// 126.210 us; speedup vs baseline: 1.1472x; 1.0097x over previous
//
#include <hip/hip_runtime.h>

#define T_TOK 8192
#define DIM   512
#define HID   1024
#define OUTD  512
#define NE    8

typedef __attribute__((ext_vector_type(8))) short short8v;   // 8 bf16 (4 VGPRs)
typedef __attribute__((ext_vector_type(4))) float f32x4;

__device__ __forceinline__ unsigned short f2bf(float f) {
  unsigned int u = __builtin_bit_cast(unsigned int, f);
  u += 0x7fffu + ((u >> 16) & 1u);            // RNE, finite inputs
  return (unsigned short)(u >> 16);
}

__device__ __forceinline__ float bf2f(unsigned short h) {
  unsigned int u = ((unsigned int)h) << 16;
  return __builtin_bit_cast(float, u);
}

__device__ __forceinline__ void gload_lds16(const void* g, void* l) {
  __builtin_amdgcn_global_load_lds(
      (__attribute__((address_space(1))) void*)g,
      (__attribute__((address_space(3))) void*)l, 16, 0, 0);
}

// gelu tanh-approx, exact identity: 0.5v(1+tanh(u)) = v * sigmoid(2u)
__device__ __forceinline__ float gelu_f(float v) {
  const float c0 = 0.7978845608028654f;       // sqrt(2/pi), jax approximate=True
  float u = c0 * (v + 0.044715f * v * v * v);
  return v / (1.0f + __expf(-2.0f * u));
}

// ============================================================================
// prep: fused {W1,W2 transpose+cvt} (blocks 0..8191) + {router} (8192..10239).
// ============================================================================
__global__ __launch_bounds__(256) void k_prep(
    const float* __restrict__ W1, const float* __restrict__ W2,
    unsigned short* __restrict__ W1t, unsigned short* __restrict__ W2t,
    const float* __restrict__ x, const float* __restrict__ Wg,
    int* __restrict__ top_e, float* __restrict__ top_p) {
  int bid = blockIdx.x;
  int tid = threadIdx.x;
  if (bid < 8192) {
    __shared__ float tile[32][33];
    int which = bid >> 12;            // 0: W1 (512x1024), 1: W2 (1024x512)
    int r = bid & 4095;
    int e = r >> 9;
    int t = r & 511;
    int R = which ? HID : DIM;
    int C = which ? OUTD : HID;
    int tx, ty;
    if (which == 0) { ty = t >> 5; tx = t & 31; }   // 16 x 32 tiles
    else            { ty = t >> 4; tx = t & 15; }   // 32 x 16 tiles
    const float* inE = (which ? W2 : W1) + (size_t)e * R * C;
    unsigned short* outE = (which ? W2t : W1t) + (size_t)e * R * C;
    int c0 = tx * 32, r0 = ty * 32;
    int xx = tid & 31, yy = tid >> 5;
#pragma unroll
    for (int i = 0; i < 32; i += 8)
      tile[yy + i][xx] = inE[(size_t)(r0 + yy + i) * C + (c0 + xx)];
    __syncthreads();
#pragma unroll
    for (int i = 0; i < 32; i += 8)
      outE[(size_t)(c0 + yy + i) * R + (r0 + xx)] = f2bf(tile[xx][yy + i]);
  } else {
    int lane = tid & 63;
    int t = (bid - 8192) * 4 + (tid >> 6);
    const float* xr = x + (size_t)t * DIM;
    int j0 = lane * 8;
    float4 xa = *(const float4*)(xr + j0);
    float4 xb = *(const float4*)(xr + j0 + 4);
    float xl[8] = {xa.x, xa.y, xa.z, xa.w, xb.x, xb.y, xb.z, xb.w};
    float acc[8] = {0.f,0.f,0.f,0.f,0.f,0.f,0.f,0.f};
#pragma unroll
    for (int jj = 0; jj < 8; ++jj) {
      float4 w0 = *(const float4*)(Wg + (size_t)(j0 + jj) * NE);
      float4 w1 = *(const float4*)(Wg + (size_t)(j0 + jj) * NE + 4);
      acc[0] += xl[jj] * w0.x; acc[1] += xl[jj] * w0.y;
      acc[2] += xl[jj] * w0.z; acc[3] += xl[jj] * w0.w;
      acc[4] += xl[jj] * w1.x; acc[5] += xl[jj] * w1.y;
      acc[6] += xl[jj] * w1.z; acc[7] += xl[jj] * w1.w;
    }
#pragma unroll
    for (int off = 32; off >= 1; off >>= 1) {
#pragma unroll
      for (int e2 = 0; e2 < 8; ++e2) acc[e2] += __shfl_xor(acc[e2], off, 64);
    }
    if (lane == 0) {
      float m = acc[0];
#pragma unroll
      for (int e2 = 1; e2 < 8; ++e2) m = fmaxf(m, acc[e2]);
      float p[8]; float s = 0.f;
#pragma unroll
      for (int e2 = 0; e2 < 8; ++e2) { p[e2] = expf(acc[e2] - m); s += p[e2]; }
      float inv = 1.f / s;
      int i0 = 0;
#pragma unroll
      for (int e2 = 1; e2 < 8; ++e2) if (p[e2] > p[i0]) i0 = e2;
      int i1 = (i0 == 0) ? 1 : 0;
#pragma unroll
      for (int e2 = 0; e2 < 8; ++e2) if (e2 != i0 && p[e2] > p[i1]) i1 = e2;
      top_e[t * 2] = i0;  top_e[t * 2 + 1] = i1;
      top_p[t * 2] = p[i0] * inv;  top_p[t * 2 + 1] = p[i1] * inv;
    }
  }
}

// ---- plan: deterministic local ranks via ballot, per-block expert counts ----
__global__ __launch_bounds__(256) void k_plan(
    const int* __restrict__ top_e, int* __restrict__ localRank,
    int* __restrict__ blockCounts) {
  __shared__ int cnt[4][NE];
  __shared__ int wbase[4][NE];
  int tid = threadIdx.x, lane = tid & 63, w = tid >> 6;
  int a = blockIdx.x * 256 + tid;
  int e = top_e[a];
  int rank = 0;
#pragma unroll
  for (int e2 = 0; e2 < NE; ++e2) {
    unsigned long long m = __ballot(e == e2);
    if (e == e2) rank = __popcll(m & ((1ULL << lane) - 1ULL));
    if (lane == 0) cnt[w][e2] = __popcll(m);
  }
  __syncthreads();
  if (tid < NE) {
    int s = 0;
#pragma unroll
    for (int w2 = 0; w2 < 4; ++w2) { wbase[w2][tid] = s; s += cnt[w2][tid]; }
    blockCounts[blockIdx.x * NE + tid] = s;
  }
  __syncthreads();
  localRank[a] = wbase[w][e] + rank;
}

// ============================================================================
// scatter with inline scan (round-12 verified).  Block 0 publishes offs[].
// ============================================================================
__global__ __launch_bounds__(256) void k_scatter(
    const float* __restrict__ x, const int* __restrict__ top_e,
    const int* __restrict__ localRank, const int* __restrict__ blockCounts,
    int* __restrict__ offs, int* __restrict__ pos_of,
    unsigned short* __restrict__ Xp) {
  __shared__ int sBase[NE];
  __shared__ int sTot[NE];
  __shared__ int sOffs[NE];
  int tid = threadIdx.x;
  int g = blockIdx.x >> 6;
  if (tid < NE) {
    int pre = 0, tot = 0;
    for (int b = 0; b < 64; ++b) {
      int c = blockCounts[b * NE + tid];
      if (b < g) pre += c;
      tot += c;
    }
    sBase[tid] = pre; sTot[tid] = tot;
  }
  __syncthreads();
  if (tid == 0) {
    int s = 0;
#pragma unroll
    for (int e = 0; e < NE; ++e) { sOffs[e] = s; s += sTot[e]; }
    if (blockIdx.x == 0) {
      for (int e = 0; e < NE; ++e) offs[e] = sOffs[e];
      offs[NE] = s;
    }
  }
  __syncthreads();
  int lane = tid & 63;
  int a = blockIdx.x * 4 + (tid >> 6);   // 0..16383
  int t = a >> 1;
  int e = top_e[a];
  int pos = sOffs[e] + sBase[e] + localRank[a];
  if (lane == 0) pos_of[a] = pos;
  const float* xr = x + (size_t)t * DIM + lane * 8;
  float4 xa = *(const float4*)xr;
  float4 xb = *(const float4*)(xr + 4);
  short8v pk;
  pk[0] = (short)f2bf(xa.x); pk[1] = (short)f2bf(xa.y);
  pk[2] = (short)f2bf(xa.z); pk[3] = (short)f2bf(xa.w);
  pk[4] = (short)f2bf(xb.x); pk[5] = (short)f2bf(xb.y);
  pk[6] = (short)f2bf(xb.z); pk[7] = (short)f2bf(xb.w);
  *(short8v*)(Xp + (size_t)pos * DIM + lane * 8) = pk;
}

#define MFMA1(d, a, b) d = __builtin_amdgcn_mfma_f32_16x16x32_bf16(a, b, d, 0, 0, 0)

// ============================================================================
// Unified grouped NT GEMM: 128x128 tile, BK=128 (NT = K/128 full-drain syncs,
// halved vs BK=64), 4 waves, single-buffer 64 KiB LDS (2 blocks/CU), XCD-
// pinned, hoisted stage addresses, XOR swizzle at 256B-row granularity
// (verified by GEMM2 round 12: passed, <=41.8 us, 0 conflicts).
// EPI=0: +bias, gelu, store bf16 H.   EPI=1: +bias, store bf16 Y.
// ============================================================================
template<int NX, int LOG2NX, int EPI>
__global__ __launch_bounds__(256, 2) void k_gemm_y(
    const unsigned short* __restrict__ A,   // [2T][K] bf16 rows (expert-grouped)
    const unsigned short* __restrict__ Bt,  // [E][N][K] bf16
    const float* __restrict__ bias, const int* __restrict__ offs,
    unsigned short* __restrict__ Hout, unsigned short* __restrict__ Ybf,
    int K, int N) {
  __shared__ __align__(16) unsigned short Al[128 * 128];  // 32 KiB
  __shared__ __align__(16) unsigned short Bl[128 * 128];  // 32 KiB

  const int e = blockIdx.x & 7;             // expert == XCD (round-robin)
  const int slot = blockIdx.x >> 3;
  const int nSlots = gridDim.x >> 3;
  const int rowBeg = offs[e], rowEnd = offs[e + 1];
  if (rowBeg >= rowEnd) return;
  const int nMT = (rowEnd - rowBeg + 127) >> 7;
  const int nWork = nMT << LOG2NX;
  const unsigned short* Be = Bt + (size_t)e * N * K;

  const int tid = threadIdx.x, lane = tid & 63, w = tid >> 6;
  const int wr = w >> 1, wc = w & 1;
  const int fr = lane & 15, fq = lane >> 4;
  const int sRow = tid >> 4;                                // 0..15
  const int sCb = (((tid & 15) << 4) ^ ((sRow & 7) << 4));  // byte off in 256B row
  const int NT = K >> 7;

  for (int idx = slot; idx < nWork; idx += nSlots) {
    const int mt = idx >> LOG2NX;
    const int xb = idx & (NX - 1);
    const int m0 = rowBeg + mt * 128;
    const int n0 = xb * 128;

    const char* aP[8];
#pragma unroll
    for (int c_ = 0; c_ < 8; ++c_) {
      int ar_ = m0 + c_ * 16 + sRow; if (ar_ > rowEnd - 1) ar_ = rowEnd - 1;
      aP[c_] = (const char*)(A + (size_t)ar_ * K) + sCb;
    }
    const char* bP0 = (const char*)(Be + (size_t)(n0 + sRow) * K) + sCb;
    const int bStride = 16 * K * 2;                         // 16 rows

    f32x4 acc[4][4];
#pragma unroll
    for (int m = 0; m < 4; ++m)
#pragma unroll
      for (int n = 0; n < 4; ++n) acc[m][n] = (f32x4){0.f, 0.f, 0.f, 0.f};

    for (int t = 0; t < NT; ++t) {
      const int tOff = t << 8;                              // 256 B per K-step
#pragma unroll
      for (int c_ = 0; c_ < 8; ++c_)
        gload_lds16(aP[c_] + tOff, (char*)&Al[0] + c_ * 4096 + (tid << 4));
#pragma unroll
      for (int c_ = 0; c_ < 8; ++c_)
        gload_lds16(bP0 + c_ * bStride + tOff, (char*)&Bl[0] + c_ * 4096 + (tid << 4));
      __syncthreads();
#pragma unroll
      for (int kk = 0; kk < 4; ++kk) {
        short8v av[4], bv[4];
#pragma unroll
        for (int m = 0; m < 4; ++m) {
          int row_ = wr * 64 + m * 16 + fr;
          av[m] = *(const short8v*)((const char*)&Al[0] + row_ * 256 +
                    (((kk << 6) + (fq << 4)) ^ ((fr & 7) << 4)));
        }
#pragma unroll
        for (int n = 0; n < 4; ++n) {
          int row_ = wc * 64 + n * 16 + fr;
          bv[n] = *(const short8v*)((const char*)&Bl[0] + row_ * 256 +
                    (((kk << 6) + (fq << 4)) ^ ((fr & 7) << 4)));
        }
#pragma unroll
        for (int m = 0; m < 4; ++m)
#pragma unroll
          for (int n = 0; n < 4; ++n)
            MFMA1(acc[m][n], av[m], bv[n]);
      }
      __syncthreads();
    }

#pragma unroll
    for (int m = 0; m < 4; ++m) {
#pragma unroll
      for (int j = 0; j < 4; ++j) {
        int row = m0 + wr * 64 + m * 16 + fq * 4 + j;
        if (row >= rowEnd) continue;
#pragma unroll
        for (int n = 0; n < 4; ++n) {
          int col = n0 + wc * 64 + n * 16 + fr;
          float v = acc[m][n][j] + bias[(size_t)e * N + col];
          if (EPI == 0) Hout[(size_t)row * N + col] = f2bf(gelu_f(v));
          else          Ybf[(size_t)row * N + col] = f2bf(v);
        }
      }
    }
  }
}

// ---- combine: out[t] = g0*Y[p0] + g1*Y[p1] (bf16 reads, f32 math/store) ----
__global__ __launch_bounds__(256) void k_combine(
    const unsigned short* __restrict__ Y, const int* __restrict__ pos_of,
    const float* __restrict__ top_p, float* __restrict__ out) {
  int lane = threadIdx.x & 63;
  int t = blockIdx.x * 4 + (threadIdx.x >> 6);
  int p0 = pos_of[t * 2], p1 = pos_of[t * 2 + 1];
  float g0 = top_p[t * 2], g1 = top_p[t * 2 + 1];
  short8v ya = *(const short8v*)(Y + (size_t)p0 * OUTD + lane * 8);
  short8v yb = *(const short8v*)(Y + (size_t)p1 * OUTD + lane * 8);
  float4 r0, r1;
  r0.x = g0 * bf2f((unsigned short)ya[0]) + g1 * bf2f((unsigned short)yb[0]);
  r0.y = g0 * bf2f((unsigned short)ya[1]) + g1 * bf2f((unsigned short)yb[1]);
  r0.z = g0 * bf2f((unsigned short)ya[2]) + g1 * bf2f((unsigned short)yb[2]);
  r0.w = g0 * bf2f((unsigned short)ya[3]) + g1 * bf2f((unsigned short)yb[3]);
  r1.x = g0 * bf2f((unsigned short)ya[4]) + g1 * bf2f((unsigned short)yb[4]);
  r1.y = g0 * bf2f((unsigned short)ya[5]) + g1 * bf2f((unsigned short)yb[5]);
  r1.z = g0 * bf2f((unsigned short)ya[6]) + g1 * bf2f((unsigned short)yb[6]);
  r1.w = g0 * bf2f((unsigned short)ya[7]) + g1 * bf2f((unsigned short)yb[7]);
  float4* o = (float4*)(out + (size_t)t * OUTD + lane * 8);
  o[0] = r0; o[1] = r1;
}

extern "C" void kernel_launch(void* const* d_in, const int* in_sizes, int n_in,
                              void* d_out, int out_size, void* d_ws, size_t ws_size,
                              hipStream_t stream) {
  const float* x  = (const float*)d_in[0];   // [T, D]
  const float* Wg = (const float*)d_in[1];   // [D, E]
  const float* W1 = (const float*)d_in[2];   // [E, D, H]
  const float* b1 = (const float*)d_in[3];   // [E, H]
  const float* W2 = (const float*)d_in[4];   // [E, H, O]
  const float* b2 = (const float*)d_in[5];   // [E, O]
  float* out = (float*)d_out;                // [T, O]

  char* p = (char*)d_ws;
  auto take = [&](size_t bytes) { char* r = p; p += (bytes + 255) & ~(size_t)255; return r; };
  unsigned short* W1t = (unsigned short*)take((size_t)NE * DIM * HID * 2);   // [E][H][D]
  unsigned short* W2t = (unsigned short*)take((size_t)NE * HID * OUTD * 2);  // [E][O][H]
  unsigned short* Xp  = (unsigned short*)take((size_t)2 * T_TOK * DIM * 2);  // [2T][D]
  unsigned short* Hb  = (unsigned short*)take((size_t)2 * T_TOK * HID * 2);  // [2T][H]
  unsigned short* Yb  = (unsigned short*)take((size_t)2 * T_TOK * OUTD * 2); // [2T][O] bf16
  int* offs   = (int*)take(4096);
  int*   top_e  = (int*)take((size_t)2 * T_TOK * 4);
  float* top_pv = (float*)take((size_t)2 * T_TOK * 4);
  int*   pos_of = (int*)take((size_t)2 * T_TOK * 4);
  int* localRank   = (int*)take((size_t)2 * T_TOK * 4);
  int* blockCounts = (int*)take((size_t)64 * NE * 4);

  const int PLAN_BLOCKS = (2 * T_TOK) / 256;   // 64

  k_prep<<<8192 + 2048, 256, 0, stream>>>(W1, W2, W1t, W2t, x, Wg, top_e, top_pv);
  k_plan<<<PLAN_BLOCKS, 256, 0, stream>>>(top_e, localRank, blockCounts);
  k_scatter<<<(2 * T_TOK) / 4, 256, 0, stream>>>(x, top_e, localRank, blockCounts,
                                                 offs, pos_of, Xp);
  k_gemm_y<8, 3, 0><<<1024, 256, 0, stream>>>(Xp, W1t, b1, offs, Hb, nullptr, DIM, HID);
  k_gemm_y<4, 2, 1><<<512, 256, 0, stream>>>(Hb, W2t, b2, offs, nullptr, Yb, HID, OUTD);
  k_combine<<<T_TOK / 4, 256, 0, stream>>>(Yb, pos_of, top_pv, out);
}